// Round 21
// baseline (230.412 us; speedup 1.0000x reference)
//
#include <hip/hip_runtime.h>

#define T_STEPS 301
#define IN_DIM  40
#define LOG2E   1.44269504088896340736f

typedef __attribute__((ext_vector_type(8))) _Float16 f16x8;
typedef __attribute__((ext_vector_type(4))) float f32x4;
typedef unsigned short ushort_t;
typedef unsigned int uint_t;

union u16cv { _Float16 hf; ushort_t u; };

#define MFMA16(A, B, C) __builtin_amdgcn_mfma_f32_16x16x32_f16((A), (B), (C), 0, 0, 0)

__device__ __forceinline__ f16x8 cvt8h(const float4 a, const float4 b) {
  f16x8 r;
  r[0] = (_Float16)a.x; r[1] = (_Float16)a.y; r[2] = (_Float16)a.z; r[3] = (_Float16)a.w;
  r[4] = (_Float16)b.x; r[5] = (_Float16)b.y; r[6] = (_Float16)b.z; r[7] = (_Float16)b.w;
  return r;
}

// z pre-scaled by log2e (2*log2e for g-gate) -> exp2-based activations.
__device__ __forceinline__ float lstm_act(float zi, float zf, float zg, float zo, float& cc) {
  const float ig = __builtin_amdgcn_rcpf(1.0f + __builtin_amdgcn_exp2f(-zi));
  const float fg = __builtin_amdgcn_rcpf(1.0f + __builtin_amdgcn_exp2f(-zf));
  const float gg = 1.0f - 2.0f * __builtin_amdgcn_rcpf(1.0f + __builtin_amdgcn_exp2f(zg));
  const float og = __builtin_amdgcn_rcpf(1.0f + __builtin_amdgcn_exp2f(-zo));
  cc = fg * cc + ig * gg;
  const float tc = 1.0f - 2.0f * __builtin_amdgcn_rcpf(1.0f + __builtin_amdgcn_exp2f(cc * (2.0f * LOG2E)));
  return og * tc;
}

// R21 = R20 + the one-line fix: ZERO the `red` epilogue buffer (R20 summed 8
// uninitialized entries per batch -> absmax 20.2). Structure unchanged:
// 256 blocks x 512 thr (8 waves = 4 pairs), 1 block/CU -> 2 waves/SIMD at
// EXACTLY R13's per-SIMD issue totals (16 MFMA, 40 trans). Pair p owns n-strip
// [16p,16p+16), zero-waste M=16. K SPLIT within a pair: u=0 computes partial z
// over h[0:32]+x[0:32] (4+4 MFMA), u=1 over h[32:64]+x[32:40]+bias. Partials
// exchanged via LDS (each wave writes the 2 acc regs it does NOT act on); act
// splits by REGISTER index (u=0: rows 4g16+{0,1}; u=1: 4g16+{2,3}) -> 2 real
// states/lane, all lanes active, 20 trans/wave. Two barriers/step.
__global__ __launch_bounds__(512, 2)
void lstm_ks(const float* __restrict__ x, const float* __restrict__ w_ih,
             const float* __restrict__ w_hh, const float* __restrict__ b_ih,
             const float* __restrict__ b_hh, const float* __restrict__ w_clf,
             const float* __restrict__ b_clf, float* __restrict__ out) {
  extern __shared__ char smem[];
  float*    wclf  = (float*)smem;                            // [301][64], 77056 B
  ushort_t* hflat = (ushort_t*)(smem + 77056);               // [2][16][64], 4096 B
  float*    zex   = (float*)(smem + 77056 + 4096);           // [4][2][4][64][2], 16384 B
  float*    red   = (float*)(smem + 77056 + 4096 + 16384);   // [8][16], 512 B

  const int tid = threadIdx.x;
  const int l   = tid & 63, wv = tid >> 6;
  const int p   = wv & 3, u = wv >> 2;
  const int c15 = l & 15, g16 = l >> 4;
  const int n   = p * 16 + c15;
  const int b0  = blockIdx.x * 16;
  const float gsc[4] = {LOG2E, LOG2E, 2.0f * LOG2E, LOG2E};

  for (int i = tid; i < (T_STEPS * 64) / 4; i += 512)
    ((float4*)wclf)[i] = ((const float4*)w_clf)[i];
  for (int i = tid; i < 1024; i += 512) ((uint_t*)hflat)[i] = 0;
  if (tid < 128) red[tid] = 0.f;          // <-- R20's missing init (the bug)

  // ---- this wave's K-half of the weights (fp16, prescaled) ----
  f16x8 whhH[4], wihH[4];
#pragma unroll
  for (int g = 0; g < 4; ++g) {
    const float s = gsc[g];
    const float* wr = w_hh + (size_t)(g * 64 + n) * 64 + u * 32 + g16 * 8;
    float4 v0 = *(const float4*)(wr);
    float4 v1 = *(const float4*)(wr + 4);
    v0.x *= s; v0.y *= s; v0.z *= s; v0.w *= s;
    v1.x *= s; v1.y *= s; v1.z *= s; v1.w *= s;
    whhH[g] = cvt8h(v0, v1);
    const float* wi = w_ih + (size_t)(g * 64 + n) * IN_DIM;
    if (u == 0) {
      float4 a0 = *(const float4*)(wi + g16 * 8);      // k = 8*g16..+7 (<32)
      float4 a1 = *(const float4*)(wi + g16 * 8 + 4);
      a0.x *= s; a0.y *= s; a0.z *= s; a0.w *= s;
      a1.x *= s; a1.y *= s; a1.z *= s; a1.w *= s;
      wihH[g] = cvt8h(a0, a1);
    } else {
      float4 a0 = make_float4(0, 0, 0, 0), a1 = make_float4(0, 0, 0, 0);
      if (g16 == 0) {                                  // k = 32..39
        a0 = *(const float4*)(wi + 32);
        a1 = *(const float4*)(wi + 36);
        a0.x *= s; a0.y *= s; a0.z *= s; a0.w *= s;
        a1.x *= s; a1.y *= s; a1.z *= s; a1.w *= s;
      } else if (g16 == 1) {                           // k = 40: bias row
        a0.x = (b_ih[g * 64 + n] + b_hh[g * 64 + n]) * s;
      }
      wihH[g] = cvt8h(a0, a1);
    }
  }
  __syncthreads();   // staging + zeroed red visible

  // ---- loop-invariant indices ----
  const int akey = (c15 >> 2) << 4;
  const int ridx = c15 * 64 + ((u * 32 + 8 * g16) ^ akey);   // own K-half h frag
  const int r0 = 2 * u, r1 = 2 * u + 1;                      // act register rows
  const int widx0 = (4 * g16 + r0) * 64 + (n ^ (g16 << 4));
  const int widx1 = (4 * g16 + r1) * 64 + (n ^ (g16 << 4));
  float* const zwr = zex + ((p * 2 + u) * 4) * 128 + l * 2;        // + g*128
  const float* const zrd = zex + ((p * 2 + (u ^ 1)) * 4) * 128 + l * 2;

  // ---- x prefetch (own K-half); u=1 lanes g16>=1 stay zero (bias via weight) ----
  const float* xb = x + (size_t)(b0 + c15) * T_STEPS * IN_DIM;
  float4 pa = make_float4(0, 0, 0, 0), pb = make_float4(0, 0, 0, 0);
  if (u == 0) {
    pa = *(const float4*)(xb + g16 * 8);
    pb = *(const float4*)(xb + g16 * 8 + 4);
  } else if (g16 == 0) {
    pa = *(const float4*)(xb + 32);
    pb = *(const float4*)(xb + 36);
  }
  f16x8 xf1c = {};
  if (g16 == 1) xf1c[0] = (_Float16)1.0f;   // k=40 bias multiplier

  f32x4 z[4];
  float cc0 = 0.f, cc1 = 0.f, acl0 = 0.f, acl1 = 0.f;

  for (int t = 0; t < T_STEPS; ++t) {
    const int rb = (t & 1) * 1024, wb = 1024 - rb;

    // own-half h A-frag
    f16x8 a = *(const f16x8*)(hflat + rb + ridx);

    // own-half x frag (u=1, g16==1 -> bias channel constant)
    f16x8 xf = cvt8h(pa, pb);
    if (u == 1 && g16 == 1) xf = xf1c;

    // partial z = xproj_half + rec_half (4 + 4 MFMA)
#pragma unroll
    for (int g = 0; g < 4; ++g) {
      f32x4 zz = {0.f, 0.f, 0.f, 0.f};
      zz = MFMA16(xf, wihH[g], zz);
      z[g] = MFMA16(a, whhH[g], zz);
    }

    // write the 2 regs we do NOT act on (partner adds them)
    if (u == 0) {
#pragma unroll
      for (int g = 0; g < 4; ++g)
        *(float2*)(zwr + g * 128) = make_float2(z[g][2], z[g][3]);
    } else {
#pragma unroll
      for (int g = 0; g < 4; ++g)
        *(float2*)(zwr + g * 128) = make_float2(z[g][0], z[g][1]);
    }

    // prefetch next x (stays in flight across barriers)
    {
      const int tn = (t + 1 < T_STEPS) ? t + 1 : t;
      const float* xp = xb + (size_t)tn * IN_DIM;
      if (u == 0) {
        pa = *(const float4*)(xp + g16 * 8);
        pb = *(const float4*)(xp + g16 * 8 + 4);
      } else if (g16 == 0) {
        pa = *(const float4*)(xp + 32);
        pb = *(const float4*)(xp + 36);
      }
    }

    asm volatile("s_waitcnt lgkmcnt(0)\n\ts_barrier" ::: "memory");   // A: z partials ready

    // add partner's partials to the regs we act on
    float2 pr0 = *(const float2*)(zrd + 0 * 128);
    float2 pr1 = *(const float2*)(zrd + 1 * 128);
    float2 pr2 = *(const float2*)(zrd + 2 * 128);
    float2 pr3 = *(const float2*)(zrd + 3 * 128);

    const float wc = wclf[t * 64 + n];
    float h0, h1;
    if (u == 0) {
      const float zi0 = z[0][0] + pr0.x, zi1 = z[0][1] + pr0.y;
      const float zf0 = z[1][0] + pr1.x, zf1 = z[1][1] + pr1.y;
      const float zg0 = z[2][0] + pr2.x, zg1 = z[2][1] + pr2.y;
      const float zo0 = z[3][0] + pr3.x, zo1 = z[3][1] + pr3.y;
      h0 = lstm_act(zi0, zf0, zg0, zo0, cc0);
      h1 = lstm_act(zi1, zf1, zg1, zo1, cc1);
    } else {
      const float zi0 = z[0][2] + pr0.x, zi1 = z[0][3] + pr0.y;
      const float zf0 = z[1][2] + pr1.x, zf1 = z[1][3] + pr1.y;
      const float zg0 = z[2][2] + pr2.x, zg1 = z[2][3] + pr2.y;
      const float zo0 = z[3][2] + pr3.x, zo1 = z[3][3] + pr3.y;
      h0 = lstm_act(zi0, zf0, zg0, zo0, cc0);
      h1 = lstm_act(zi1, zf1, zg1, zo1, cc1);
    }
    acl0 += h0 * wc;
    acl1 += h1 * wc;
    u16cv cv0, cv1;
    cv0.hf = (_Float16)h0;
    cv1.hf = (_Float16)h1;
    hflat[wb + widx0] = cv0.u;
    hflat[wb + widx1] = cv1.u;

    if (t == T_STEPS - 1) break;   // uniform across grid
    asm volatile("s_waitcnt lgkmcnt(0)\n\ts_barrier" ::: "memory");   // B: h ready
  }

  // ---- epilogue: reduce over c15 lanes, then across waves ----
#pragma unroll
  for (int m = 1; m <= 8; m <<= 1) {
    acl0 += __shfl_xor(acl0, m);
    acl1 += __shfl_xor(acl1, m);
  }
  if (c15 == 0) {
    red[wv * 16 + 4 * g16 + r0] = acl0;
    red[wv * 16 + 4 * g16 + r1] = acl1;
  }
  __syncthreads();
  if (tid < 16) {
    float s = b_clf[0];
#pragma unroll
    for (int w2 = 0; w2 < 8; ++w2) s += red[w2 * 16 + tid];
    out[b0 + tid] = s;
  }
}

extern "C" void kernel_launch(void* const* d_in, const int* in_sizes, int n_in,
                              void* d_out, int out_size, void* d_ws, size_t ws_size,
                              hipStream_t stream) {
  const float* x     = (const float*)d_in[0];
  const float* w_ih  = (const float*)d_in[1];
  const float* w_hh  = (const float*)d_in[2];
  const float* b_ih  = (const float*)d_in[3];
  const float* b_hh  = (const float*)d_in[4];
  const float* w_clf = (const float*)d_in[5];
  const float* b_clf = (const float*)d_in[6];
  float* out = (float*)d_out;

  const size_t shmem = 77056 + 4096 + 16384 + 512;   // ~95.8 KB dynamic LDS
  (void)hipFuncSetAttribute((const void*)lstm_ks,
                            hipFuncAttributeMaxDynamicSharedMemorySize, (int)shmem);
  lstm_ks<<<256, 512, shmem, stream>>>(x, w_ih, w_hh, b_ih, b_hh, w_clf, b_clf, out);
}

// Round 22
// 173.361 us; speedup vs baseline: 1.3291x; 1.3291x over previous
//
#include <hip/hip_runtime.h>

#define T_STEPS 301
#define IN_DIM  40
#define LOG2E   1.44269504088896340736f

typedef __attribute__((ext_vector_type(8))) _Float16 f16x8;
typedef __attribute__((ext_vector_type(4))) float f32x4;
typedef unsigned short ushort_t;
typedef unsigned int uint_t;

union u16cv { _Float16 hf; ushort_t u; };

#define MFMA16(A, B, C) __builtin_amdgcn_mfma_f32_16x16x32_f16((A), (B), (C), 0, 0, 0)

__device__ __forceinline__ f16x8 cvt8h(const float4 a, const float4 b) {
  f16x8 r;
  r[0] = (_Float16)a.x; r[1] = (_Float16)a.y; r[2] = (_Float16)a.z; r[3] = (_Float16)a.w;
  r[4] = (_Float16)b.x; r[5] = (_Float16)b.y; r[6] = (_Float16)b.z; r[7] = (_Float16)b.w;
  return r;
}

// z pre-scaled by log2e (2*log2e for g-gate) -> exp2-based activations.
__device__ __forceinline__ float lstm_act(float zi, float zf, float zg, float zo, float& cc) {
  const float ig = __builtin_amdgcn_rcpf(1.0f + __builtin_amdgcn_exp2f(-zi));
  const float fg = __builtin_amdgcn_rcpf(1.0f + __builtin_amdgcn_exp2f(-zf));
  const float gg = 1.0f - 2.0f * __builtin_amdgcn_rcpf(1.0f + __builtin_amdgcn_exp2f(zg));
  const float og = __builtin_amdgcn_rcpf(1.0f + __builtin_amdgcn_exp2f(-zo));
  cc = fg * cc + ig * gg;
  const float tc = 1.0f - 2.0f * __builtin_amdgcn_rcpf(1.0f + __builtin_amdgcn_exp2f(cc * (2.0f * LOG2E)));
  return og * tc;
}

// FINAL (R14 structure, measured 173.9 us): 256 blocks x 256 thr (4 waves),
// 1 block/CU, zero-waste M=16 decomposition. Block = 16 batches; wave w owns
// hidden strip n in [16w,16w+16) for ALL 4 gates (activation fully in-register,
// no z exchange). A rows = the 16 batches (all live); 8 xproj + 8 recurrent
// MFMA per wave/step. Software-pipelined step with z/zn ping-pong:
//   barrier -> ds_read h -> rec MFMA(t) on z ->
//   [ xproj(t+1) MFMAs into zn + x cvt/prefetch | act(t) transcendentals ] ->
//   write h (fp16, XOR-swizzled) -> barrier.
// Bias enters via the dead k=40 input channel; wclf staged in LDS; weights
// prescaled by log2e (2*log2e for g) so activations use native exp2.
// Converged: latency-bound serial recurrence (all pipes <40% busy); the
// structure-space around it (multi-wave, K-split, q-pack, SGB, stagger, ILP)
// measured slower in R6-R21.
__global__ __launch_bounds__(256, 1)
void lstm_pp(const float* __restrict__ x, const float* __restrict__ w_ih,
             const float* __restrict__ w_hh, const float* __restrict__ b_ih,
             const float* __restrict__ b_hh, const float* __restrict__ w_clf,
             const float* __restrict__ b_clf, float* __restrict__ out) {
  extern __shared__ char smem[];
  float*    wclf  = (float*)smem;                       // [301][64], 77056 B
  ushort_t* hflat = (ushort_t*)(smem + 77056);          // [2][16][64], 4096 B
  float*    red   = (float*)(smem + 77056 + 4096);      // [4][16], 256 B

  const int tid = threadIdx.x;
  const int l   = tid & 63, w = tid >> 6;
  const int c15 = l & 15, g16 = l >> 4;
  const int n   = w * 16 + c15;
  const int b0  = blockIdx.x * 16;
  const float gsc[4] = {LOG2E, LOG2E, 2.0f * LOG2E, LOG2E};

  for (int i = tid; i < (T_STEPS * 64) / 4; i += 256)
    ((float4*)wclf)[i] = ((const float4*)w_clf)[i];
  for (int i = tid; i < 1024; i += 256) ((uint_t*)hflat)[i] = 0;

  // ---- weights in registers (fp16, prescaled); bias via k=40 channel ----
  f16x8 whh[4][2], wih[4][2];
#pragma unroll
  for (int g = 0; g < 4; ++g) {
    const float s = gsc[g];
    const float* wr = w_hh + (size_t)(g * 64 + n) * 64;
#pragma unroll
    for (int kc = 0; kc < 2; ++kc) {
      float4 v0 = *(const float4*)(wr + kc * 32 + g16 * 8);
      float4 v1 = *(const float4*)(wr + kc * 32 + g16 * 8 + 4);
      v0.x *= s; v0.y *= s; v0.z *= s; v0.w *= s;
      v1.x *= s; v1.y *= s; v1.z *= s; v1.w *= s;
      whh[g][kc] = cvt8h(v0, v1);
    }
    const float* wi = w_ih + (size_t)(g * 64 + n) * IN_DIM;
    {
      float4 v0 = *(const float4*)(wi + g16 * 8);
      float4 v1 = *(const float4*)(wi + g16 * 8 + 4);
      v0.x *= s; v0.y *= s; v0.z *= s; v0.w *= s;
      v1.x *= s; v1.y *= s; v1.z *= s; v1.w *= s;
      wih[g][0] = cvt8h(v0, v1);
    }
    {
      float4 u0 = make_float4(0, 0, 0, 0), u1 = make_float4(0, 0, 0, 0);
      if (g16 == 0) {
        u0 = *(const float4*)(wi + 32);
        u1 = *(const float4*)(wi + 36);
        u0.x *= s; u0.y *= s; u0.z *= s; u0.w *= s;
        u1.x *= s; u1.y *= s; u1.z *= s; u1.w *= s;
      } else if (g16 == 1) {
        u0.x = (b_ih[g * 64 + n] + b_hh[g * 64 + n]) * s;   // k=40 bias row
      }
      wih[g][1] = cvt8h(u0, u1);
    }
  }
  __syncthreads();

  // loop-invariant LDS indices (XOR-swizzled h exchange)
  const int akey = (c15 >> 2) << 4;
  const int ridx0 = c15 * 64 + ((0 * 32 + 8 * g16) ^ akey);
  const int ridx1 = c15 * 64 + ((1 * 32 + 8 * g16) ^ akey);
  int widx[4];
#pragma unroll
  for (int r = 0; r < 4; ++r) widx[r] = (4 * g16 + r) * 64 + (n ^ (g16 << 4));

  const float* xb = x + (size_t)(b0 + c15) * T_STEPS * IN_DIM;
  f16x8 xf1c = {};
  if (g16 == 1) xf1c[0] = (_Float16)1.0f;   // k=40 bias multiplier

  f32x4 z[4], zn[4];
  float cc[4]  = {0.f, 0.f, 0.f, 0.f};
  float acl[4] = {0.f, 0.f, 0.f, 0.f};

  // ---- prologue: xproj(t=0) directly into z; prefetch x[1] ----
  {
    const float4 v0 = *(const float4*)(xb + g16 * 8);
    const float4 v1 = *(const float4*)(xb + g16 * 8 + 4);
    f16x8 xf0 = cvt8h(v0, v1);
    f16x8 xf1 = xf1c;
    if (g16 == 0) {
      const float4 u0 = *(const float4*)(xb + 32);
      const float4 u1 = *(const float4*)(xb + 36);
      xf1 = cvt8h(u0, u1);
    }
#pragma unroll
    for (int g = 0; g < 4; ++g) {
      f32x4 zz = {0.f, 0.f, 0.f, 0.f};
      zz = MFMA16(xf0, wih[g][0], zz);
      z[g] = MFMA16(xf1, wih[g][1], zz);
    }
  }
  float4 px0, px1, pq0 = make_float4(0, 0, 0, 0), pq1 = make_float4(0, 0, 0, 0);
  {
    const float* xp = xb + IN_DIM;       // x[1]
    px0 = *(const float4*)(xp + g16 * 8);
    px1 = *(const float4*)(xp + g16 * 8 + 4);
    if (g16 == 0) {
      pq0 = *(const float4*)(xp + 32);
      pq1 = *(const float4*)(xp + 36);
    }
  }

  // STEP: rec(t) on ZC; act(t) from ZC interleaved with xproj(t+1) into ZN.
#define STEP(ZC, ZN, T, LAST)                                                     \
  {                                                                               \
    const int rb = ((T) & 1) * 1024, wb = 1024 - rb;                              \
    f16x8 a0 = *(const f16x8*)(hflat + rb + ridx0);                               \
    f16x8 a1 = *(const f16x8*)(hflat + rb + ridx1);                               \
    _Pragma("unroll")                                                             \
    for (int g = 0; g < 4; ++g) {                                                 \
      ZC[g] = MFMA16(a0, whh[g][0], ZC[g]);                                       \
      ZC[g] = MFMA16(a1, whh[g][1], ZC[g]);                                       \
    }                                                                             \
    if (!(LAST)) {                                                                \
      f16x8 xf0 = cvt8h(px0, px1);                                                \
      f16x8 xf1 = xf1c;                                                           \
      if (g16 == 0) xf1 = cvt8h(pq0, pq1);                                        \
      _Pragma("unroll")                                                           \
      for (int g = 0; g < 4; ++g) {                                               \
        f32x4 zz = {0.f, 0.f, 0.f, 0.f};                                          \
        zz = MFMA16(xf0, wih[g][0], zz);                                          \
        ZN[g] = MFMA16(xf1, wih[g][1], zz);                                       \
      }                                                                           \
      const int tn = ((T) + 2 < T_STEPS) ? (T) + 2 : T_STEPS - 1;                 \
      const float* xp = xb + (size_t)tn * IN_DIM;                                 \
      px0 = *(const float4*)(xp + g16 * 8);                                       \
      px1 = *(const float4*)(xp + g16 * 8 + 4);                                   \
      if (g16 == 0) {                                                             \
        pq0 = *(const float4*)(xp + 32);                                          \
        pq1 = *(const float4*)(xp + 36);                                          \
      }                                                                           \
    }                                                                             \
    const float wc = wclf[(T) * 64 + n];                                          \
    _Pragma("unroll")                                                             \
    for (int r = 0; r < 4; ++r) {                                                 \
      const float h = lstm_act(ZC[0][r], ZC[1][r], ZC[2][r], ZC[3][r], cc[r]);    \
      acl[r] += h * wc;                                                           \
      u16cv cv; cv.hf = (_Float16)h;                                              \
      hflat[wb + widx[r]] = cv.u;                                                 \
    }                                                                             \
    asm volatile("s_waitcnt lgkmcnt(0)\n\ts_barrier" ::: "memory");               \
  }

  for (int p = 0; p < 150; ++p) {
    const int t0 = 2 * p;
    STEP(z, zn, t0, 0)
    STEP(zn, z, t0 + 1, 0)
  }
  STEP(z, zn, 300, 1)
#undef STEP

  // ---- epilogue: reduce acl over c15 lanes, then across waves ----
#pragma unroll
  for (int m = 1; m <= 8; m <<= 1) {
#pragma unroll
    for (int r = 0; r < 4; ++r) acl[r] += __shfl_xor(acl[r], m);
  }
  if (c15 == 0) {
#pragma unroll
    for (int r = 0; r < 4; ++r) red[w * 16 + 4 * g16 + r] = acl[r];
  }
  __syncthreads();
  if (tid < 16)
    out[b0 + tid] = b_clf[0] + red[tid] + red[16 + tid] + red[32 + tid] + red[48 + tid];
}

extern "C" void kernel_launch(void* const* d_in, const int* in_sizes, int n_in,
                              void* d_out, int out_size, void* d_ws, size_t ws_size,
                              hipStream_t stream) {
  const float* x     = (const float*)d_in[0];
  const float* w_ih  = (const float*)d_in[1];
  const float* w_hh  = (const float*)d_in[2];
  const float* b_ih  = (const float*)d_in[3];
  const float* b_hh  = (const float*)d_in[4];
  const float* w_clf = (const float*)d_in[5];
  const float* b_clf = (const float*)d_in[6];
  float* out = (float*)d_out;

  const size_t shmem = 77056 + 4096 + 256;   // ~79.5 KB dynamic LDS
  (void)hipFuncSetAttribute((const void*)lstm_pp,
                            hipFuncAttributeMaxDynamicSharedMemorySize, (int)shmem);
  lstm_pp<<<256, 256, shmem, stream>>>(x, w_ih, w_hh, b_ih, b_hh, w_clf, b_clf, out);
}